// Round 2
// baseline (470.570 us; speedup 1.0000x reference)
//
#include <hip/hip_runtime.h>

// HealEncoding v4: persistent, barrier-free steady state.
// (Resubmission — round 1 bench failed with GPUAcquisitionTimeout, no data.)
//
// Thread mapping: tid -> (bl = tid>>2 pixel-in-tile, l = tid&3 level), so ONE
// wave holds 16 pixels x 4 levels. A row's 8 outputs live within the wave:
// one __shfl_xor pairs adjacent levels and each lane stores a coalesced
// float2 straight from registers -> no sout staging, NO __syncthreads in the
// tile loop (v3 paid a vmcnt(0)+lgkmcnt(0) block-wide drain twice per tile).
// Grid-stride persistent blocks stage the 25 KB table ONCE (v3 re-staged it
// 7813x = 396 MB of L2 reads + a startup latency chain per block).
//
// params        [4, 792, 2]  f32   (25 KB -> LDS, loaded once per block)
// pixel_latlon  [4, B, 2]    f32
// neigh_latlon  [4, 8B, 2]   f32   (element i = j*B + b)
// pixel_index   [4, B]       i32
// neigh_index   [4, 8, B]    i32   (-1 = missing -> contributes 0)
// out           [B, 8]       f32   out[b, 4*f + l] = res[l][b][f]

#define NLEV 4
#define MAXSZ 792
#define TABSZ (NLEV * MAXSZ * 2)   // 6336 floats = 25344 B
#define PPB 64                     // pixels per tile (block = 256 = 64 px x 4 lvl)

__global__ __launch_bounds__(256, 6) void heal_encoding_kernel(
    const float* __restrict__ params,
    const float* __restrict__ pixel_latlon,
    const float* __restrict__ neigh_latlon,
    const int*   __restrict__ pixel_index,
    const int*   __restrict__ neigh_index,
    float* __restrict__ out,
    int B, int ntiles)
{
    __shared__ float stab[TABSZ];   // 25344 B -> 6 blocks/CU by LDS

    const int tid = threadIdx.x;
    const int bl  = tid >> 2;      // pixel within tile
    const int l   = tid & 3;       // level 0..3

    // ---- stage table once per persistent block ----
    {
        const float4* p4  = (const float4*)params;
        float4*       st4 = (float4*)stab;
        for (int i = tid; i < TABSZ / 4; i += 256)
            st4[i] = p4[i];
    }
    __syncthreads();               // the ONLY barrier this block ever executes

    const float2* sp2  = (const float2*)stab;
    const float2* pll2 = (const float2*)pixel_latlon;
    const float2* nll2 = (const float2*)neigh_latlon;
    const int lb = l * MAXSZ;      // table base for this level (float2 units)
    const int pb = l * B;          // base into pixel arrays
    const int nb = l * 8 * B;      // base into neigh arrays (<= 24e6, int ok)

    for (int t = blockIdx.x; t < ntiles; t += gridDim.x) {
        const int b_raw = t * PPB + bl;
        const int b = min(b_raw, B - 1);   // clamp -> loads unconditional

        // ---- issue all 18 loads back-to-back, no consumers between ----
        const int    pi  = pixel_index[pb + b];
        const float2 pll = pll2[pb + b];
        int    ni[8];
        float2 nl[8];
        #pragma unroll
        for (int j = 0; j < 8; ++j) {
            ni[j] = neigh_index[nb + j * B + b];
            nl[j] = nll2[nb + j * B + b];
        }

        // ---- pure LDS + VALU ----
        float a0 = 0.0f, a1 = 0.0f;
        #pragma unroll
        for (int j = 0; j < 8; ++j) {
            float dth = nl[j].x - pll.x;
            float dph = nl[j].y - pll.y;
            float d   = sqrtf(dth * dth + dph * dph);
            float w   = (ni[j] >= 0) ? (1.0f / d) : 0.0f;    // mask -> exactly 0
            float2 r  = sp2[lb + (ni[j] >= 0 ? ni[j] : 0)];
            a0 += w * r.x;
            a1 += w * r.y;
        }
        float2 m = sp2[lb + (pi < 0 ? 768 : pi)];            // residual last
        a0 += m.x;
        a1 += m.y;

        // ---- pair adjacent levels in-wave, store float2 from registers ----
        // row b layout: [f0l0 f0l1 f0l2 f0l3 f1l0 f1l1 f1l2 f1l3]
        // even lane sends a1 (partner's f1 word), odd lane sends a0.
        const bool odd = (l & 1);
        float x = __shfl_xor(odd ? a0 : a1, 1);
        float2 st = odd ? make_float2(x, a1)    // {f1[l-1], f1[l]} at col 4+(l-1)
                        : make_float2(a0, x);   // {f0[l],   f0[l+1]} at col l
        const int col = odd ? (l + 3) : l;      // l=1->4, l=3->6, l=0->0, l=2->2
        if (b_raw < B)
            *(float2*)(out + (size_t)b_raw * 8 + col) = st;
    }
}

extern "C" void kernel_launch(void* const* d_in, const int* in_sizes, int n_in,
                              void* d_out, int out_size, void* d_ws, size_t ws_size,
                              hipStream_t stream) {
    const float* params       = (const float*)d_in[0];
    const float* pixel_latlon = (const float*)d_in[1];
    const float* neigh_latlon = (const float*)d_in[2];
    const int*   pixel_index  = (const int*)d_in[3];
    const int*   neigh_index  = (const int*)d_in[4];
    float* out = (float*)d_out;

    int B = in_sizes[3] / NLEV;              // pixel_index has 4*B elements
    int ntiles = (B + PPB - 1) / PPB;        // B=1e6 -> 15625, exact (no tail)
    int blocks = 1536;                        // 256 CU x 6 blocks/CU resident
    if (blocks > ntiles) blocks = ntiles;
    heal_encoding_kernel<<<blocks, 256, 0, stream>>>(
        params, pixel_latlon, neigh_latlon, pixel_index, neigh_index, out, B, ntiles);
}